// Round 10
// baseline (210.021 us; speedup 1.0000x reference)
//
#include <hip/hip_runtime.h>
#include <math.h>

#define ZEPS  0.01f
#define ZMEAN 0.1307f
#define ZSIGMA 0.3081f

constexpr int D = 1024, H = 4096, O = 10;
constexpr size_t HD = (size_t)H * D;

using short8  = __attribute__((ext_vector_type(8))) short;
using ushort8 = __attribute__((ext_vector_type(8))) unsigned short;
using f32x4   = __attribute__((ext_vector_type(4))) float;
typedef unsigned short ushort_t;

__device__ inline unsigned short f2bf(float x) {  // RNE fp32 -> bf16 bits
    unsigned int u = __float_as_uint(x);
    u += 0x7FFFu + ((u >> 16) & 1u);
    return (unsigned short)(u >> 16);
}
__device__ inline float bf2f(unsigned short h) {
    return __uint_as_float(((unsigned int)h) << 16);
}
// round-half-up fp32 pair -> packed bf16x2
__device__ inline unsigned int f2bf2_fast(float a, float b) {
    unsigned int ua = __float_as_uint(a) + 0x8000u;
    unsigned int ub = __float_as_uint(b) + 0x8000u;
    return (ua >> 16) | (ub & 0xFFFF0000u);
}

// async 16B/lane global->LDS (lds dest = base + lane*16, wave-uniform base)
__device__ inline void gl_lds16(const void* g, void* l) {
    __builtin_amdgcn_global_load_lds(
        (const __attribute__((address_space(1))) unsigned int*)g,
        (__attribute__((address_space(3))) unsigned int*)l, 16, 0, 0);
}

__device__ inline float zval(float xv) {
    float up = fminf(xv + ZEPS, 1.f);
    float lo = fmaxf(xv - ZEPS, 0.f);
    return (up + lo - ZMEAN) / ZSIGMA;
}
__device__ inline float zdia(float xv) {
    return fminf(xv + ZEPS, 1.f) / ZSIGMA;
}

__device__ inline void relu_params(float v, float r, float& vout, float& aout, float& tout) {
    float u = v + r, l = v - r;
    float denom = u - l;
    float slope = u / (denom == 0.f ? 1.f : denom);
    float term = (1.f - slope) * u * 0.5f;
    bool dead = (u <= 0.f);
    bool crossing = (u > 0.f) && (l < 0.f);
    vout = dead ? 0.f : (crossing ? (slope * v + term) : v);
    aout = dead ? 0.f : (crossing ? slope : 1.f);
    tout = (!dead && crossing) ? term : 0.f;
}

// ---------------------------------------------------------------------------
// wave-per-row: v1 = W1@values+b1 ; r1 = |W1| @ d ; ReLU-1 params  [R7 verbatim]
__global__ __launch_bounds__(256) void k_layer1(const float* __restrict__ W1, const float* __restrict__ b1,
                                                const float* __restrict__ x,
                                                float* __restrict__ v1p, float* __restrict__ a1,
                                                float* __restrict__ t1) {
    int wid = threadIdx.x >> 6, lane = threadIdx.x & 63;
    int i = blockIdx.x * 4 + wid;
    const float* row = W1 + (size_t)i * D;
    float sv = 0.f, sr = 0.f;
#pragma unroll
    for (int it = 0; it < 4; ++it) {
        int j = it * 256 + lane * 4;
        float4 w = *(const float4*)&row[j];
        float4 xx = *(const float4*)&x[j];
        sv += w.x * zval(xx.x) + w.y * zval(xx.y) + w.z * zval(xx.z) + w.w * zval(xx.w);
        sr += fabsf(w.x) * zdia(xx.x) + fabsf(w.y) * zdia(xx.y) +
              fabsf(w.z) * zdia(xx.z) + fabsf(w.w) * zdia(xx.w);
    }
#pragma unroll
    for (int m = 1; m <= 32; m <<= 1) {
        sv += __shfl_xor(sv, m, 64);
        sr += __shfl_xor(sr, m, 64);
    }
    if (lane == 0) {
        float vo, ao, to;
        relu_params(sv + b1[i], sr, vo, ao, to);
        v1p[i] = vo; a1[i] = ao; t1[i] = to;
    }
}

// W1sT[j][k] = bf16( a1[k] * W1[k][j] * d[j] )  [R7 verbatim]
__global__ __launch_bounds__(256) void k_scaleT(const float* __restrict__ W1, const float* __restrict__ a1,
                                                const float* __restrict__ x,
                                                ushort_t* __restrict__ W1sT) {
    __shared__ float tile[32][33];
    int j0 = blockIdx.x * 32, k0 = blockIdx.y * 32;
    int r = threadIdx.x >> 3;
    int c = (threadIdx.x & 7) * 4;
    float4 w = *(const float4*)&W1[(size_t)(k0 + r) * D + j0 + c];
    float4 xx = *(const float4*)&x[j0 + c];
    float a = a1[k0 + r];
    tile[r][c + 0] = a * w.x * zdia(xx.x);
    tile[r][c + 1] = a * w.y * zdia(xx.y);
    tile[r][c + 2] = a * w.z * zdia(xx.z);
    tile[r][c + 3] = a * w.w * zdia(xx.w);
    __syncthreads();
    ushort4 o;
    o.x = f2bf(tile[c + 0][r]);
    o.y = f2bf(tile[c + 1][r]);
    o.z = f2bf(tile[c + 2][r]);
    o.w = f2bf(tile[c + 3][r]);
    *(ushort4*)&W1sT[(size_t)(j0 + r) * H + k0 + c] = o;
}

// ---------------------------------------------------------------------------
// eps2(bf16) = bf16(W2) @ W1sT^T, split-K=2, XCD remap, dbuf pipeline.  [R7 verbatim]
#define GBK 64
__global__ __launch_bounds__(256) void k_gemm_mfma(const float* __restrict__ A,
                                                   const ushort_t* __restrict__ B,
                                                   const float* __restrict__ v1p,
                                                   const float* __restrict__ t1,
                                                   ushort_t* __restrict__ C,
                                                   float* __restrict__ vpart,
                                                   float* __restrict__ tpart) {
    const int N = D, K = H;
    __shared__ __align__(16) ushort_t As[2][128 * GBK];   // 2 x 16 KB
    __shared__ __align__(16) ushort_t Bs[2][128 * GBK];   // 2 x 16 KB
    __shared__ float vt[2048], tt[2048];                  // 16 KB
    int b = blockIdx.x;
    int u = b & 7, v = b >> 3;
    int z = u >> 2;
    int y = (u & 3) * 8 + (v >> 3);
    int xb = v & 7;
    int tid = threadIdx.x;
    int wave = tid >> 6, lane = tid & 63;
    int bm = y * 128, bn = xb * 128;
    int kbeg = z * (K / 2);
    ushort_t* Cz = C + (size_t)z * HD;
    int wm = (wave >> 1) * 64, wn = (wave & 1) * 64;

    int srow = lane >> 3, sc = lane & 7, scp = sc ^ srow;
    int r15 = lane & 15, quad = lane >> 4, key = r15 & 7;
    int rowg = tid >> 3, ch = tid & 7;
    int aswz = ch ^ (rowg & 7);

    const int S = (K / 2) / GBK;  // 32

    float4 pa[4][2];
    float sv[4] = {0.f, 0.f, 0.f, 0.f}, st[4] = {0.f, 0.f, 0.f, 0.f};

    auto issueA = [&](int s) {
#pragma unroll
        for (int g = 0; g < 4; ++g) {
            const float* ap = &A[(size_t)(bm + g * 32 + rowg) * K + kbeg + s * GBK + ch * 8];
            pa[g][0] = *(const float4*)ap;
            pa[g][1] = *(const float4*)(ap + 4);
        }
    };
    auto issueB = [&](int s, int buf) {
#pragma unroll
        for (int g = 0; g < 4; ++g) {
            int row = wave * 32 + g * 8;
            gl_lds16(&B[(size_t)(bn + row + srow) * K + kbeg + s * GBK + scp * 8], &Bs[buf][row * GBK]);
        }
    };
    auto cvtwrite = [&](int s, int buf) {
        if ((s & 7) == xb) {
            const float* vp = &vt[s * 64 + ch * 8];
            const float* tp = &tt[s * 64 + ch * 8];
            float4 v0 = *(const float4*)vp, v1 = *(const float4*)(vp + 4);
            float4 t0 = *(const float4*)tp, t1v = *(const float4*)(tp + 4);
#pragma unroll
            for (int g = 0; g < 4; ++g) {
                sv[g] += pa[g][0].x * v0.x + pa[g][0].y * v0.y + pa[g][0].z * v0.z + pa[g][0].w * v0.w
                       + pa[g][1].x * v1.x + pa[g][1].y * v1.y + pa[g][1].z * v1.z + pa[g][1].w * v1.w;
                st[g] += pa[g][0].x * t0.x + pa[g][0].y * t0.y + pa[g][0].z * t0.z + pa[g][0].w * t0.w
                       + pa[g][1].x * t1v.x + pa[g][1].y * t1v.y + pa[g][1].z * t1v.z + pa[g][1].w * t1v.w;
            }
        }
#pragma unroll
        for (int g = 0; g < 4; ++g) {
            uint4 hh;
            hh.x = f2bf2_fast(pa[g][0].x, pa[g][0].y);
            hh.y = f2bf2_fast(pa[g][0].z, pa[g][0].w);
            hh.z = f2bf2_fast(pa[g][1].x, pa[g][1].y);
            hh.w = f2bf2_fast(pa[g][1].z, pa[g][1].w);
            *(uint4*)&As[buf][(g * 32 + rowg) * GBK + aswz * 8] = hh;
        }
    };

    f32x4 acc[4][4];
#pragma unroll
    for (int p = 0; p < 4; ++p)
#pragma unroll
        for (int q = 0; q < 4; ++q) acc[p][q] = (f32x4){0.f, 0.f, 0.f, 0.f};

    // prologue
    issueA(0);
    issueB(0, 0);
    for (int idx = tid; idx < 512; idx += 256) {
        *(float4*)&vt[idx * 4] = *(const float4*)&v1p[kbeg + idx * 4];
        *(float4*)&tt[idx * 4] = *(const float4*)&t1[kbeg + idx * 4];
    }
    __syncthreads();
    cvtwrite(0, 0);
    __syncthreads();

    for (int s = 0; s < S; ++s) {
        int buf = s & 1, nbuf = buf ^ 1;
        if (s + 1 < S) {
            issueA(s + 1);
            issueB(s + 1, nbuf);
        }
#pragma unroll
        for (int kk = 0; kk < 2; ++kk) {
            short8 af[4], bf[4];
#pragma unroll
            for (int mt = 0; mt < 4; ++mt)
                af[mt] = *(const short8*)&As[buf][(wm + mt * 16 + r15) * GBK + (((kk * 4 + quad) ^ key)) * 8];
#pragma unroll
            for (int nt = 0; nt < 4; ++nt)
                bf[nt] = *(const short8*)&Bs[buf][(wn + nt * 16 + r15) * GBK + (((kk * 4 + quad) ^ key)) * 8];
#pragma unroll
            for (int mt = 0; mt < 4; ++mt)
#pragma unroll
                for (int nt = 0; nt < 4; ++nt)
                    acc[mt][nt] = __builtin_amdgcn_mfma_f32_16x16x32_bf16(af[mt], bf[nt], acc[mt][nt], 0, 0, 0);
        }
        if (s + 1 < S) cvtwrite(s + 1, nbuf);
        __syncthreads();
    }

#pragma unroll
    for (int mt = 0; mt < 4; ++mt) {
        int gr = bm + wm + mt * 16 + quad * 4;
#pragma unroll
        for (int nt = 0; nt < 4; ++nt) {
            int gc = bn + wn + nt * 16 + r15;
            Cz[(size_t)(gr + 0) * N + gc] = f2bf(acc[mt][nt][0]);
            Cz[(size_t)(gr + 1) * N + gc] = f2bf(acc[mt][nt][1]);
            Cz[(size_t)(gr + 2) * N + gc] = f2bf(acc[mt][nt][2]);
            Cz[(size_t)(gr + 3) * N + gc] = f2bf(acc[mt][nt][3]);
        }
    }

#pragma unroll
    for (int g = 0; g < 4; ++g) {
        float a = sv[g], bb = st[g];
        a += __shfl_xor(a, 1, 64); a += __shfl_xor(a, 2, 64); a += __shfl_xor(a, 4, 64);
        bb += __shfl_xor(bb, 1, 64); bb += __shfl_xor(bb, 2, 64); bb += __shfl_xor(bb, 4, 64);
        if (ch == 0) {
            int i = bm + g * 32 + rowg;
            vpart[(size_t)(z * 8 + xb) * H + i] = a;
            tpart[(size_t)(z * 8 + xb) * H + i] = bb;
        }
    }
}

// ---------------------------------------------------------------------------
// Fused relu2 + w3s + eps3-partials. 256 blocks x 16 rows each.
// Phase A (4 rows/wave): r2 = rowsum|e1+e2|, v2/t2col from 16 vpart/tpart
// partials, ReLU-2 params; w3s for the block rows -> LDS.
// Phase B: thread j-group of 4 cols accumulates sum_i(block rows) w3s[i][o]*e[i][j]
// (rows L2-hot from phase A) -> pbuf[o][blk][j].
__global__ __launch_bounds__(256) void k_mid(const ushort_t* __restrict__ e1, const ushort_t* __restrict__ e2,
                                             const float* __restrict__ vpart, const float* __restrict__ tpart,
                                             const float* __restrict__ b2, const float* __restrict__ W3,
                                             float* __restrict__ v2p, float* __restrict__ a2,
                                             float* __restrict__ t2, float* __restrict__ t2col,
                                             float* __restrict__ pbuf) {
    __shared__ float sa2[16];
    __shared__ float sw3[16][O];
    int blk = blockIdx.x, tid = threadIdx.x;
    int wave = tid >> 6, lane = tid & 63;

#pragma unroll
    for (int r = 0; r < 4; ++r) {
        int ii = wave * 4 + r;
        int i = blk * 16 + ii;
        size_t off = (size_t)i * D + lane * 16;
        ushort8 a0 = *(const ushort8*)&e1[off];
        ushort8 a1v = *(const ushort8*)&e1[off + 8];
        ushort8 b0 = *(const ushort8*)&e2[off];
        ushort8 b1v = *(const ushort8*)&e2[off + 8];
        float s = 0.f;
#pragma unroll
        for (int q = 0; q < 8; ++q)
            s += fabsf(bf2f(a0[q]) + bf2f(b0[q])) + fabsf(bf2f(a1v[q]) + bf2f(b1v[q]));
        float ve = (lane < 16) ? vpart[(size_t)lane * H + i] : 0.f;
        float te = (lane < 16) ? tpart[(size_t)lane * H + i] : 0.f;
#pragma unroll
        for (int m = 1; m <= 32; m <<= 1) {
            s += __shfl_xor(s, m, 64);
            ve += __shfl_xor(ve, m, 64);
            te += __shfl_xor(te, m, 64);
        }
        if (lane == 0) {
            float vo, ao, to;
            relu_params(ve + b2[i], s + fabsf(te), vo, ao, to);
            v2p[i] = vo; a2[i] = ao; t2[i] = to; t2col[i] = te; sa2[ii] = ao;
        }
    }
    __syncthreads();
    if (tid < 16 * O) {
        int ii = tid / O, o = tid % O;
        sw3[ii][o] = W3[(size_t)o * H + blk * 16 + ii] * sa2[ii];
    }
    __syncthreads();

    int j = tid * 4;
    float acc[4][O];
#pragma unroll
    for (int c = 0; c < 4; ++c)
#pragma unroll
        for (int o = 0; o < O; ++o) acc[c][o] = 0.f;
#pragma unroll
    for (int ii = 0; ii < 16; ++ii) {
        size_t off = (size_t)(blk * 16 + ii) * D + j;
        ushort4 za = *(const ushort4*)&e1[off];
        ushort4 zb = *(const ushort4*)&e2[off];
        float e0 = bf2f(za.x) + bf2f(zb.x);
        float ee1 = bf2f(za.y) + bf2f(zb.y);
        float ee2 = bf2f(za.z) + bf2f(zb.z);
        float ee3 = bf2f(za.w) + bf2f(zb.w);
        const float* w = sw3[ii];
#pragma unroll
        for (int o = 0; o < O; ++o) {
            float wo = w[o];
            acc[0][o] += wo * e0; acc[1][o] += wo * ee1;
            acc[2][o] += wo * ee2; acc[3][o] += wo * ee3;
        }
    }
#pragma unroll
    for (int o = 0; o < O; ++o) {
        float4 stv = make_float4(acc[0][o], acc[1][o], acc[2][o], acc[3][o]);
        *(float4*)&pbuf[((size_t)o * 256 + blk) * D + j] = stv;
    }
}

// ---------------------------------------------------------------------------
// final: r3[o] = sum_j |sum_s pbuf[o][s][j]| (slice-major coalesced);
// three H-dots; output u/l. 10 blocks x 1024 threads.
__global__ __launch_bounds__(1024) void k_final(const float* __restrict__ W3, const float* __restrict__ b3,
                                                const float* __restrict__ v2p, const float* __restrict__ a2,
                                                const float* __restrict__ t2col, const float* __restrict__ t2,
                                                const float* __restrict__ pbuf, float* __restrict__ out) {
    int o = blockIdx.x, tid = threadIdx.x;
    float t = 0.f;
    const float* pb = pbuf + (size_t)o * 256 * D;
    for (int s = 0; s < 256; ++s) t += pb[(size_t)s * D + tid];
    float s3 = fabsf(t);

    const float* row = W3 + (size_t)o * H;
    float sv = 0.f, s1 = 0.f, s2 = 0.f;
#pragma unroll
    for (int it = 0; it < 4; ++it) {
        int i = it * 1024 + tid;
        float w = row[i];
        sv += w * v2p[i];
        s1 += w * a2[i] * t2col[i];
        s2 += w * t2[i];
    }
    __shared__ float red[4][1024];  // 16 KB
    red[0][tid] = sv; red[1][tid] = s1; red[2][tid] = s2; red[3][tid] = s3;
    __syncthreads();
    for (int off2 = 512; off2; off2 >>= 1) {
        if (tid < off2) {
            red[0][tid] += red[0][tid + off2];
            red[1][tid] += red[1][tid + off2];
            red[2][tid] += red[2][tid + off2];
            red[3][tid] += red[3][tid + off2];
        }
        __syncthreads();
    }
    if (tid == 0) {
        float v3 = red[0][0] + b3[o];
        float rr = red[3][0] + fabsf(red[1][0]) + fabsf(red[2][0]);
        out[o] = v3 + rr;       // u
        out[O + o] = v3 - rr;   // l
    }
}

// ---------------------------------------------------------------------------
extern "C" void kernel_launch(void* const* d_in, const int* in_sizes, int n_in,
                              void* d_out, int out_size, void* d_ws, size_t ws_size,
                              hipStream_t stream) {
    const float* x  = (const float*)d_in[0];
    const float* W1 = (const float*)d_in[1];
    const float* b1 = (const float*)d_in[2];
    const float* W2 = (const float*)d_in[3];
    const float* b2 = (const float*)d_in[4];
    const float* W3 = (const float*)d_in[5];
    const float* b3 = (const float*)d_in[6];
    float* out = (float*)d_out;

    float* p = (float*)d_ws;
    float* v1p   = p; p += H;
    float* a1    = p; p += H;
    float* t1    = p; p += H;
    float* t2col = p; p += H;
    float* v2p   = p; p += H;
    float* a2    = p; p += H;
    float* t2    = p; p += H;
    float* vpart = p; p += 16 * H;
    float* tpart = p; p += 16 * H;
    float* pbuf  = p; p += (size_t)O * 256 * D;               // 10 MB
    ushort_t* eps2 = (ushort_t*)p;                            // 2 x 8 MB bf16 (split-K partials)
    ushort_t* W1sT = eps2 + 2 * HD;                           // 8 MB bf16
    ushort_t* eps2b = eps2 + HD;

    k_layer1<<<H / 4, 256, 0, stream>>>(W1, b1, x, v1p, a1, t1);
    k_scaleT<<<dim3(D / 32, H / 32), 256, 0, stream>>>(W1, a1, x, W1sT);
    k_gemm_mfma<<<512, 256, 0, stream>>>(W2, W1sT, v1p, t1, eps2, vpart, tpart);
    k_mid<<<256, 256, 0, stream>>>(eps2, eps2b, vpart, tpart, b2, W3, v2p, a2, t2, t2col, pbuf);
    k_final<<<O, 1024, 0, stream>>>(W3, b3, v2p, a2, t2col, t2, pbuf, out);
}

// Round 11
// 207.026 us; speedup vs baseline: 1.0145x; 1.0145x over previous
//
#include <hip/hip_runtime.h>
#include <math.h>

#define ZEPS  0.01f
#define ZMEAN 0.1307f
#define ZSIGMA 0.3081f

constexpr int D = 1024, H = 4096, O = 10;
constexpr size_t HD = (size_t)H * D;

using short8  = __attribute__((ext_vector_type(8))) short;
using ushort8 = __attribute__((ext_vector_type(8))) unsigned short;
using f32x4   = __attribute__((ext_vector_type(4))) float;
typedef unsigned short ushort_t;

__device__ inline unsigned short f2bf(float x) {  // RNE fp32 -> bf16 bits
    unsigned int u = __float_as_uint(x);
    u += 0x7FFFu + ((u >> 16) & 1u);
    return (unsigned short)(u >> 16);
}
__device__ inline float bf2f(unsigned short h) {
    return __uint_as_float(((unsigned int)h) << 16);
}

// async 16B/lane global->LDS (lds dest = base + lane*16, wave-uniform base)
__device__ inline void gl_lds16(const void* g, void* l) {
    __builtin_amdgcn_global_load_lds(
        (const __attribute__((address_space(1))) unsigned int*)g,
        (__attribute__((address_space(3))) unsigned int*)l, 16, 0, 0);
}

__device__ inline float zval(float xv) {
    float up = fminf(xv + ZEPS, 1.f);
    float lo = fmaxf(xv - ZEPS, 0.f);
    return (up + lo - ZMEAN) / ZSIGMA;
}
__device__ inline float zdia(float xv) {
    return fminf(xv + ZEPS, 1.f) / ZSIGMA;
}

__device__ inline void relu_params(float v, float r, float& vout, float& aout, float& tout) {
    float u = v + r, l = v - r;
    float denom = u - l;
    float slope = u / (denom == 0.f ? 1.f : denom);
    float term = (1.f - slope) * u * 0.5f;
    bool dead = (u <= 0.f);
    bool crossing = (u > 0.f) && (l < 0.f);
    vout = dead ? 0.f : (crossing ? (slope * v + term) : v);
    aout = dead ? 0.f : (crossing ? slope : 1.f);
    tout = (!dead && crossing) ? term : 0.f;
}

// ---------------------------------------------------------------------------
// wave-per-row layer1 + zeroing of the stats buffer (r3/dots/counter)
__global__ __launch_bounds__(256) void k_layer1(const float* __restrict__ W1, const float* __restrict__ b1,
                                                const float* __restrict__ x,
                                                float* __restrict__ v1p, float* __restrict__ a1,
                                                float* __restrict__ t1, float* __restrict__ sbuf) {
    if (blockIdx.x == 0 && threadIdx.x < 96) sbuf[threadIdx.x] = 0.f;
    int wid = threadIdx.x >> 6, lane = threadIdx.x & 63;
    int i = blockIdx.x * 4 + wid;
    const float* row = W1 + (size_t)i * D;
    float sv = 0.f, sr = 0.f;
#pragma unroll
    for (int it = 0; it < 4; ++it) {
        int j = it * 256 + lane * 4;
        float4 w = *(const float4*)&row[j];
        float4 xx = *(const float4*)&x[j];
        sv += w.x * zval(xx.x) + w.y * zval(xx.y) + w.z * zval(xx.z) + w.w * zval(xx.w);
        sr += fabsf(w.x) * zdia(xx.x) + fabsf(w.y) * zdia(xx.y) +
              fabsf(w.z) * zdia(xx.z) + fabsf(w.w) * zdia(xx.w);
    }
#pragma unroll
    for (int m = 1; m <= 32; m <<= 1) {
        sv += __shfl_xor(sv, m, 64);
        sr += __shfl_xor(sr, m, 64);
    }
    if (lane == 0) {
        float vo, ao, to;
        relu_params(sv + b1[i], sr, vo, ao, to);
        v1p[i] = vo; a1[i] = ao; t1[i] = to;
    }
}

// W1sT[j][k] = bf16( a1[k] * W1[k][j] * d[j] )
__global__ __launch_bounds__(256) void k_scaleT(const float* __restrict__ W1, const float* __restrict__ a1,
                                                const float* __restrict__ x,
                                                ushort_t* __restrict__ W1sT) {
    __shared__ float tile[32][33];
    int j0 = blockIdx.x * 32, k0 = blockIdx.y * 32;
    int r = threadIdx.x >> 3;
    int c = (threadIdx.x & 7) * 4;
    float4 w = *(const float4*)&W1[(size_t)(k0 + r) * D + j0 + c];
    float4 xx = *(const float4*)&x[j0 + c];
    float a = a1[k0 + r];
    tile[r][c + 0] = a * w.x * zdia(xx.x);
    tile[r][c + 1] = a * w.y * zdia(xx.y);
    tile[r][c + 2] = a * w.z * zdia(xx.z);
    tile[r][c + 3] = a * w.w * zdia(xx.w);
    __syncthreads();
    ushort4 o;
    o.x = f2bf(tile[c + 0][r]);
    o.y = f2bf(tile[c + 1][r]);
    o.z = f2bf(tile[c + 2][r]);
    o.w = f2bf(tile[c + 3][r]);
    *(ushort4*)&W1sT[(size_t)(j0 + r) * H + k0 + c] = o;
}

// W2 -> bf16 stream, fused v2 = W2@v1p + b2, t2col = W2@t1 (wave per row)
__global__ __launch_bounds__(256) void k_conv(const float* __restrict__ W2, const float* __restrict__ b2,
                                              const float* __restrict__ v1p, const float* __restrict__ t1,
                                              float* __restrict__ v2, float* __restrict__ t2col,
                                              ushort_t* __restrict__ W2b) {
    __shared__ float vt[4096], tt[4096];  // 32 KB
    int tid = threadIdx.x, wave = tid >> 6, lane = tid & 63;
    for (int idx = tid; idx < 1024; idx += 256) {
        *(float4*)&vt[idx * 4] = *(const float4*)&v1p[idx * 4];
        *(float4*)&tt[idx * 4] = *(const float4*)&t1[idx * 4];
    }
    __syncthreads();
    int i = blockIdx.x * 4 + wave;
    const float* row = W2 + (size_t)i * H;
    ushort_t* orow = W2b + (size_t)i * H;
    float sv = 0.f, st = 0.f;
#pragma unroll 4
    for (int it = 0; it < 16; ++it) {
        int j = it * 256 + lane * 4;
        float4 w = *(const float4*)&row[j];
        float4 vv = *(const float4*)&vt[j];
        float4 tv = *(const float4*)&tt[j];
        sv += w.x * vv.x + w.y * vv.y + w.z * vv.z + w.w * vv.w;
        st += w.x * tv.x + w.y * tv.y + w.z * tv.z + w.w * tv.w;
        ushort4 o;
        o.x = f2bf(w.x); o.y = f2bf(w.y); o.z = f2bf(w.z); o.w = f2bf(w.w);
        *(ushort4*)&orow[j] = o;
    }
#pragma unroll
    for (int m = 1; m <= 32; m <<= 1) { sv += __shfl_xor(sv, m, 64); st += __shfl_xor(st, m, 64); }
    if (lane == 0) { v2[i] = sv + b2[i]; t2col[i] = st; }
}

// ---------------------------------------------------------------------------
// eps2(bf16) = W2b @ W1sT^T, pure-bf16, tile 128x256, split-K=2, single-buffer.
// Grid 256, XCD remap: u=b&7 owns 8 (y,z) A-tiles, 4 xb blocks each share one
// A-tile within the XCD's L2. 64 MFMA/wave/step; XOR chunk swizzle (0 conflicts).
#define GBK 64
__global__ __launch_bounds__(256, 2) void k_gemm_mfma(const ushort_t* __restrict__ A,
                                                      const ushort_t* __restrict__ B,
                                                      ushort_t* __restrict__ C) {
    const int K = H;
    __shared__ __align__(16) ushort_t As[128 * GBK];  // 16 KB
    __shared__ __align__(16) ushort_t Bs[256 * GBK];  // 32 KB
    int b = blockIdx.x;
    int u = b & 7, v = b >> 3;
    int t = u * 8 + (v >> 2);     // 0..63 (y,z) tile id
    int z = t >> 5, y = t & 31, xb = v & 3;
    int tid = threadIdx.x;
    int wave = tid >> 6, lane = tid & 63;
    int bm = y * 128, bn = xb * 256, kbeg = z * 2048;
    ushort_t* Cz = C + (size_t)z * HD;
    int wm = (wave >> 1) * 64, wn = (wave & 1) * 128;
    int srow = lane >> 3, sc = lane & 7, scp = sc ^ srow;
    int r15 = lane & 15, quad = lane >> 4, key = r15 & 7;

    f32x4 acc[4][8];
#pragma unroll
    for (int p = 0; p < 4; ++p)
#pragma unroll
        for (int q = 0; q < 8; ++q) acc[p][q] = (f32x4){0.f, 0.f, 0.f, 0.f};

    for (int s = 0; s < 32; ++s) {
        int k0 = kbeg + s * GBK;
#pragma unroll
        for (int g = 0; g < 4; ++g) {
            int row = wave * 32 + g * 8;
            gl_lds16(&A[(size_t)(bm + row + srow) * K + k0 + scp * 8], &As[row * GBK]);
        }
#pragma unroll
        for (int g = 0; g < 8; ++g) {
            int row = wave * 64 + g * 8;
            gl_lds16(&B[(size_t)(bn + row + srow) * K + k0 + scp * 8], &Bs[row * GBK]);
        }
        __syncthreads();
#pragma unroll
        for (int kk = 0; kk < 2; ++kk) {
            short8 af[4], bf[8];
#pragma unroll
            for (int mt = 0; mt < 4; ++mt)
                af[mt] = *(const short8*)&As[(wm + mt * 16 + r15) * GBK + ((kk * 4 + quad) ^ key) * 8];
#pragma unroll
            for (int nt = 0; nt < 8; ++nt)
                bf[nt] = *(const short8*)&Bs[(wn + nt * 16 + r15) * GBK + ((kk * 4 + quad) ^ key) * 8];
#pragma unroll
            for (int mt = 0; mt < 4; ++mt)
#pragma unroll
                for (int nt = 0; nt < 8; ++nt)
                    acc[mt][nt] = __builtin_amdgcn_mfma_f32_16x16x32_bf16(af[mt], bf[nt], acc[mt][nt], 0, 0, 0);
        }
        __syncthreads();
    }

#pragma unroll
    for (int mt = 0; mt < 4; ++mt) {
        int gr = bm + wm + mt * 16 + quad * 4;
#pragma unroll
        for (int nt = 0; nt < 8; ++nt) {
            int gc = bn + wn + nt * 16 + r15;
            Cz[(size_t)(gr + 0) * D + gc] = f2bf(acc[mt][nt][0]);
            Cz[(size_t)(gr + 1) * D + gc] = f2bf(acc[mt][nt][1]);
            Cz[(size_t)(gr + 2) * D + gc] = f2bf(acc[mt][nt][2]);
            Cz[(size_t)(gr + 3) * D + gc] = f2bf(acc[mt][nt][3]);
        }
    }
}

// ---------------------------------------------------------------------------
// Fused relu2 + w3s + eps3-partials. 256 blocks x 16 rows each.
__global__ __launch_bounds__(256) void k_mid(const ushort_t* __restrict__ e1, const ushort_t* __restrict__ e2,
                                             const float* __restrict__ v2, const float* __restrict__ t2col,
                                             const float* __restrict__ W3,
                                             float* __restrict__ v2p, float* __restrict__ a2,
                                             float* __restrict__ t2, float* __restrict__ pbuf) {
    __shared__ float sa2[16];
    __shared__ float sw3[16][O];
    int blk = blockIdx.x, tid = threadIdx.x;
    int wave = tid >> 6, lane = tid & 63;
    int base = blk * 16;

#pragma unroll
    for (int r = 0; r < 4; ++r) {
        int ii = wave * 4 + r;
        int i = base + ii;
        size_t off = (size_t)i * D + lane * 16;
        ushort8 a0 = *(const ushort8*)&e1[off];
        ushort8 a1v = *(const ushort8*)&e1[off + 8];
        ushort8 b0 = *(const ushort8*)&e2[off];
        ushort8 b1v = *(const ushort8*)&e2[off + 8];
        float s = 0.f;
#pragma unroll
        for (int q = 0; q < 8; ++q)
            s += fabsf(bf2f(a0[q]) + bf2f(b0[q])) + fabsf(bf2f(a1v[q]) + bf2f(b1v[q]));
#pragma unroll
        for (int m = 1; m <= 32; m <<= 1) s += __shfl_xor(s, m, 64);
        if (lane == 0) {
            float vo, ao, to;
            relu_params(v2[i], s + fabsf(t2col[i]), vo, ao, to);
            v2p[i] = vo; a2[i] = ao; t2[i] = to; sa2[ii] = ao;
        }
    }
    __syncthreads();
    if (tid < 16 * O) {
        int ii = tid / O, o = tid % O;
        sw3[ii][o] = W3[(size_t)o * H + base + ii] * sa2[ii];
    }
    __syncthreads();

    int j = tid * 4;
    float acc[4][O];
#pragma unroll
    for (int c = 0; c < 4; ++c)
#pragma unroll
        for (int o = 0; o < O; ++o) acc[c][o] = 0.f;
#pragma unroll
    for (int ii = 0; ii < 16; ++ii) {
        size_t off = (size_t)(base + ii) * D + j;
        ushort4 za = *(const ushort4*)&e1[off];
        ushort4 zb = *(const ushort4*)&e2[off];
        float e0 = bf2f(za.x) + bf2f(zb.x);
        float ee1 = bf2f(za.y) + bf2f(zb.y);
        float ee2 = bf2f(za.z) + bf2f(zb.z);
        float ee3 = bf2f(za.w) + bf2f(zb.w);
        const float* w = sw3[ii];
#pragma unroll
        for (int o = 0; o < O; ++o) {
            float wo = w[o];
            acc[0][o] += wo * e0; acc[1][o] += wo * ee1;
            acc[2][o] += wo * ee2; acc[3][o] += wo * ee3;
        }
    }
#pragma unroll
    for (int o = 0; o < O; ++o) {
        float4 stv = make_float4(acc[0][o], acc[1][o], acc[2][o], acc[3][o]);
        *(float4*)&pbuf[((size_t)o * 256 + blk) * D + j] = stv;
    }
}

// ---------------------------------------------------------------------------
// Partial finisher: grid (8, O) x 128 threads. Block (g,o): r3-partial over a
// 128-col strip (coalesced across 256 slices) + 512-row dot strips; atomicAdd
// into sbuf; last-done block writes out via device-scope atomic reads.
// sbuf layout: [0..15] r3, [16..31] dv, [32..47] d1, [48..63] d2, [64] counter.
__global__ __launch_bounds__(128) void k_final2(const float* __restrict__ W3, const float* __restrict__ b3,
                                                const float* __restrict__ v2p, const float* __restrict__ a2,
                                                const float* __restrict__ t2col, const float* __restrict__ t2,
                                                const float* __restrict__ pbuf, float* __restrict__ sbuf,
                                                float* __restrict__ out) {
    int g = blockIdx.x, o = blockIdx.y, tid = threadIdx.x;
    int j = g * 128 + tid;
    float tsum = 0.f;
    const float* pb = pbuf + (size_t)o * 256 * D;
    for (int s = 0; s < 256; ++s) tsum += pb[(size_t)s * D + j];
    float s3 = fabsf(tsum);

    const float* row = W3 + (size_t)o * H;
    float sv = 0.f, s1 = 0.f, s2 = 0.f;
#pragma unroll
    for (int it = 0; it < 4; ++it) {
        int i = g * 512 + it * 128 + tid;
        float w = row[i];
        sv += w * v2p[i];
        s1 += w * a2[i] * t2col[i];
        s2 += w * t2[i];
    }
    __shared__ float red[4][128];
    red[0][tid] = s3; red[1][tid] = sv; red[2][tid] = s1; red[3][tid] = s2;
    __syncthreads();
    for (int off = 64; off; off >>= 1) {
        if (tid < off) {
            red[0][tid] += red[0][tid + off];
            red[1][tid] += red[1][tid + off];
            red[2][tid] += red[2][tid + off];
            red[3][tid] += red[3][tid + off];
        }
        __syncthreads();
    }
    __shared__ int isLast;
    if (tid == 0) {
        atomicAdd(&sbuf[o], red[0][0]);
        atomicAdd(&sbuf[16 + o], red[1][0]);
        atomicAdd(&sbuf[32 + o], red[2][0]);
        atomicAdd(&sbuf[48 + o], red[3][0]);
        __threadfence();
        int old = atomicAdd((int*)&sbuf[64], 1);
        isLast = (old == 8 * O - 1);
    }
    __syncthreads();
    if (isLast) {
        __threadfence();
        if (tid < O) {
            int o2 = tid;
            float r3v = atomicAdd(&sbuf[o2], 0.f);
            float dvv = atomicAdd(&sbuf[16 + o2], 0.f);
            float d1v = atomicAdd(&sbuf[32 + o2], 0.f);
            float d2v = atomicAdd(&sbuf[48 + o2], 0.f);
            float v3 = dvv + b3[o2];
            float rr = r3v + fabsf(d1v) + fabsf(d2v);
            out[o2] = v3 + rr;       // u
            out[O + o2] = v3 - rr;   // l
        }
    }
}

// ---------------------------------------------------------------------------
extern "C" void kernel_launch(void* const* d_in, const int* in_sizes, int n_in,
                              void* d_out, int out_size, void* d_ws, size_t ws_size,
                              hipStream_t stream) {
    const float* x  = (const float*)d_in[0];
    const float* W1 = (const float*)d_in[1];
    const float* b1 = (const float*)d_in[2];
    const float* W2 = (const float*)d_in[3];
    const float* b2 = (const float*)d_in[4];
    const float* W3 = (const float*)d_in[5];
    const float* b3 = (const float*)d_in[6];
    float* out = (float*)d_out;

    float* p = (float*)d_ws;
    float* v1p   = p; p += H;
    float* a1    = p; p += H;
    float* t1    = p; p += H;
    float* v2    = p; p += H;
    float* t2col = p; p += H;
    float* v2p   = p; p += H;
    float* a2    = p; p += H;
    float* t2    = p; p += H;
    float* sbuf  = p; p += 96;
    p += 32;  // 16B alignment pad
    float* pbuf  = p; p += (size_t)O * 256 * D;               // 10 MB
    ushort_t* eps2 = (ushort_t*)p;                            // 2 x 8 MB bf16 (split-K partials)
    ushort_t* W1sT = eps2 + 2 * HD;                           // 8 MB bf16
    ushort_t* W2b  = W1sT + HD;                               // 32 MB bf16
    ushort_t* eps2b = eps2 + HD;

    k_layer1<<<H / 4, 256, 0, stream>>>(W1, b1, x, v1p, a1, t1, sbuf);
    k_scaleT<<<dim3(D / 32, H / 32), 256, 0, stream>>>(W1, a1, x, W1sT);
    k_conv<<<H / 4, 256, 0, stream>>>(W2, b2, v1p, t1, v2, t2col, W2b);
    k_gemm_mfma<<<256, 256, 0, stream>>>(W2b, W1sT, eps2);
    k_mid<<<256, 256, 0, stream>>>(eps2, eps2b, v2, t2col, W3, v2p, a2, t2, pbuf);
    k_final2<<<dim3(8, O), 128, 0, stream>>>(W3, b3, v2p, a2, t2col, t2, pbuf, sbuf, out);
}